// Round 1
// baseline (324.750 us; speedup 1.0000x reference)
//
#include <hip/hip_runtime.h>
#include <math.h>

// Problem geometry (fixed by setup_inputs)
#define BB   256   // batch
#define DIN  2048  // layer-0 input dim
#define HH   512   // hidden dim
#define NSL  4     // i-chunk split for wavelet kernels

#define NEG_HALF_LOG2E (-0.72134752044448170368f)

// ---------------------------------------------------------------------------
// r = 1 / (A_MIN + softplus(s_raw) + 1e-8)   for all three layers in one launch
// ---------------------------------------------------------------------------
__global__ __launch_bounds__(256) void prep_all_k(
    const float* __restrict__ s0, const float* __restrict__ s1, const float* __restrict__ s2,
    float* __restrict__ r0, float* __restrict__ r1, float* __restrict__ r2)
{
    int i = blockIdx.x * 256 + threadIdx.x;
    const float* s; float* r; int j;
    if (i < HH * DIN)            { s = s0; r = r0; j = i; }
    else if (i < HH*DIN + HH*HH) { s = s1; r = r1; j = i - HH*DIN; }
    else                         { s = s2; r = r2; j = i - (HH*DIN + HH*HH); }
    float v  = s[j];
    // numerically stable softplus
    float sp = fmaxf(v, 0.0f) + log1pf(__expf(-fabsf(v)));
    r[j] = 1.0f / (0.001f + sp + 1e-8f);
}

// ---------------------------------------------------------------------------
// transpose x [BB][DIN] -> xT [DIN][BB]
// ---------------------------------------------------------------------------
__global__ __launch_bounds__(256) void transpose_k(
    const float* __restrict__ in, float* __restrict__ out)
{
    __shared__ float tile[32][33];
    int c0 = blockIdx.x * 32;           // column (DIN) tile
    int r0 = blockIdx.y * 32;           // row (BB) tile
    int tx = threadIdx.x, ty = threadIdx.y;   // block (32, 8)
#pragma unroll
    for (int k = 0; k < 4; k++)
        tile[ty + 8*k][tx] = in[(size_t)(r0 + ty + 8*k) * DIN + c0 + tx];
    __syncthreads();
#pragma unroll
    for (int k = 0; k < 4; k++)
        out[(size_t)(c0 + ty + 8*k) * BB + r0 + tx] = tile[tx][ty + 8*k];
}

// ---------------------------------------------------------------------------
// zero small stats region (3 layers x 512 floats)
// ---------------------------------------------------------------------------
__global__ void zero_k(float* __restrict__ p)
{
    p[blockIdx.x * 256 + threadIdx.x] = 0.0f;
}

// ---------------------------------------------------------------------------
// wavelet partial sums.
// fin: [D][BB] feature-major activations; tt/rr/ww: [HH][D]
// zp : [NSL][HH][BB] partial sums (one slice per i-chunk)
// block: 256 threads = 256 b's; each thread handles 4 consecutive o rows.
// grid: (HH/4, NSL)
// ---------------------------------------------------------------------------
__device__ __forceinline__ float wav_eval(float x, float t, float r, float w)
{
    float d  = (x - t) * r;
    float s2 = d * d;
    float e  = __builtin_amdgcn_exp2f(s2 * NEG_HALF_LOG2E);
    return (1.0f - s2) * e * w;
}

template<int D>
__global__ __launch_bounds__(256) void wav_partial_k(
    const float* __restrict__ fin,
    const float* __restrict__ tt,
    const float* __restrict__ rr,
    const float* __restrict__ ww,
    float* __restrict__ zp)
{
    constexpr int CH = D / NSL;
    const int o0 = blockIdx.x * 4;
    const int i0 = blockIdx.y * CH;
    const int b  = threadIdx.x;

    const float* __restrict__ xc = fin + b;
    const float* __restrict__ tp0 = tt + (size_t)(o0 + 0) * D;
    const float* __restrict__ tp1 = tt + (size_t)(o0 + 1) * D;
    const float* __restrict__ tp2 = tt + (size_t)(o0 + 2) * D;
    const float* __restrict__ tp3 = tt + (size_t)(o0 + 3) * D;
    const float* __restrict__ rp0 = rr + (size_t)(o0 + 0) * D;
    const float* __restrict__ rp1 = rr + (size_t)(o0 + 1) * D;
    const float* __restrict__ rp2 = rr + (size_t)(o0 + 2) * D;
    const float* __restrict__ rp3 = rr + (size_t)(o0 + 3) * D;
    const float* __restrict__ wp0 = ww + (size_t)(o0 + 0) * D;
    const float* __restrict__ wp1 = ww + (size_t)(o0 + 1) * D;
    const float* __restrict__ wp2 = ww + (size_t)(o0 + 2) * D;
    const float* __restrict__ wp3 = ww + (size_t)(o0 + 3) * D;

    float a0 = 0.f, a1 = 0.f, a2 = 0.f, a3 = 0.f;

    for (int i = i0; i < i0 + CH; i += 4) {
        float x0 = xc[(size_t)(i + 0) * BB];
        float x1 = xc[(size_t)(i + 1) * BB];
        float x2 = xc[(size_t)(i + 2) * BB];
        float x3 = xc[(size_t)(i + 3) * BB];

        float4 t0v = *(const float4*)(tp0 + i);
        float4 r0v = *(const float4*)(rp0 + i);
        float4 w0v = *(const float4*)(wp0 + i);
        a0 += wav_eval(x0, t0v.x, r0v.x, w0v.x);
        a0 += wav_eval(x1, t0v.y, r0v.y, w0v.y);
        a0 += wav_eval(x2, t0v.z, r0v.z, w0v.z);
        a0 += wav_eval(x3, t0v.w, r0v.w, w0v.w);

        float4 t1v = *(const float4*)(tp1 + i);
        float4 r1v = *(const float4*)(rp1 + i);
        float4 w1v = *(const float4*)(wp1 + i);
        a1 += wav_eval(x0, t1v.x, r1v.x, w1v.x);
        a1 += wav_eval(x1, t1v.y, r1v.y, w1v.y);
        a1 += wav_eval(x2, t1v.z, r1v.z, w1v.z);
        a1 += wav_eval(x3, t1v.w, r1v.w, w1v.w);

        float4 t2v = *(const float4*)(tp2 + i);
        float4 r2v = *(const float4*)(rp2 + i);
        float4 w2v = *(const float4*)(wp2 + i);
        a2 += wav_eval(x0, t2v.x, r2v.x, w2v.x);
        a2 += wav_eval(x1, t2v.y, r2v.y, w2v.y);
        a2 += wav_eval(x2, t2v.z, r2v.z, w2v.z);
        a2 += wav_eval(x3, t2v.w, r2v.w, w2v.w);

        float4 t3v = *(const float4*)(tp3 + i);
        float4 r3v = *(const float4*)(rp3 + i);
        float4 w3v = *(const float4*)(wp3 + i);
        a3 += wav_eval(x0, t3v.x, r3v.x, w3v.x);
        a3 += wav_eval(x1, t3v.y, r3v.y, w3v.y);
        a3 += wav_eval(x2, t3v.z, r3v.z, w3v.z);
        a3 += wav_eval(x3, t3v.w, r3v.w, w3v.w);
    }

    float* __restrict__ zs = zp + (size_t)blockIdx.y * (HH * BB);
    zs[(size_t)(o0 + 0) * BB + b] = a0;
    zs[(size_t)(o0 + 1) * BB + b] = a1;
    zs[(size_t)(o0 + 2) * BB + b] = a2;
    zs[(size_t)(o0 + 3) * BB + b] = a3;
}

// ---------------------------------------------------------------------------
// combine partials + SiLU + per-b stats (atomics).  grid HH, block 256.
// zp slice0 is overwritten in place with silu(y).
// stats: [0..255]=sum, [256..511]=sumsq
// ---------------------------------------------------------------------------
__global__ __launch_bounds__(256) void silu_stats_k(
    float* __restrict__ zp, float* __restrict__ stats)
{
    int idx = blockIdx.x * 256 + threadIdx.x;
    float y = zp[idx] + zp[idx + HH*BB] + zp[idx + 2*HH*BB] + zp[idx + 3*HH*BB];
    float v = y / (1.0f + __expf(-y));
    zp[idx] = v;
    int b = threadIdx.x;
    atomicAdd(&stats[b], v);
    atomicAdd(&stats[256 + b], v * v);
}

// ---------------------------------------------------------------------------
// layernorm: fout[o][b] = g[o]*(z[o][b]-m[b])*rsqrt(var[b]+eps) + be[o]
// grid HH, block 256
// ---------------------------------------------------------------------------
__global__ __launch_bounds__(256) void norm_k(
    const float* __restrict__ z, const float* __restrict__ stats,
    const float* __restrict__ g, const float* __restrict__ be,
    float* __restrict__ fout)
{
    int o = blockIdx.x, b = threadIdx.x;
    float m   = stats[b] * (1.0f / HH);
    float var = stats[256 + b] * (1.0f / HH) - m * m;
    float rs  = rsqrtf(var + 1e-5f);
    float v   = z[(size_t)o * BB + b];
    fout[(size_t)o * BB + b] = g[o] * (v - m) * rs + be[o];
}

// ---------------------------------------------------------------------------
// classifier: out[b][c] = sum_o f[o][b]*cw[c][o] + cb[c]   (C=2)
// one block, 256 threads (thread = b)
// ---------------------------------------------------------------------------
__global__ __launch_bounds__(256) void cls_k(
    const float* __restrict__ f, const float* __restrict__ cw,
    const float* __restrict__ cb, float* __restrict__ out)
{
    int b = threadIdx.x;
    float a0 = cb[0], a1 = cb[1];
#pragma unroll 8
    for (int o = 0; o < HH; o++) {
        float v = f[(size_t)o * BB + b];
        a0 = fmaf(v, cw[o],       a0);
        a1 = fmaf(v, cw[HH + o],  a1);
    }
    out[b * 2 + 0] = a0;
    out[b * 2 + 1] = a1;
}

// ---------------------------------------------------------------------------
extern "C" void kernel_launch(void* const* d_in, const int* in_sizes, int n_in,
                              void* d_out, int out_size, void* d_ws, size_t ws_size,
                              hipStream_t stream)
{
    const float* x  = (const float*)d_in[0];
    const float* t0 = (const float*)d_in[1];
    const float* s0 = (const float*)d_in[2];
    const float* w0 = (const float*)d_in[3];
    const float* g0 = (const float*)d_in[4];
    const float* b0 = (const float*)d_in[5];
    const float* t1 = (const float*)d_in[6];
    const float* s1 = (const float*)d_in[7];
    const float* w1 = (const float*)d_in[8];
    const float* g1 = (const float*)d_in[9];
    const float* b1 = (const float*)d_in[10];
    const float* t2 = (const float*)d_in[11];
    const float* s2 = (const float*)d_in[12];
    const float* w2 = (const float*)d_in[13];
    const float* g2 = (const float*)d_in[14];
    const float* b2 = (const float*)d_in[15];
    const float* cw = (const float*)d_in[16];
    const float* cb = (const float*)d_in[17];
    float* out = (float*)d_out;

    float* ws = (float*)d_ws;
    // workspace layout (floats)
    float* r0p   = ws;                          // HH*DIN       = 1048576
    float* r1p   = r0p + (size_t)HH * DIN;      // HH*HH        = 262144
    float* r2p   = r1p + (size_t)HH * HH;       // 262144
    float* xT    = r2p + (size_t)HH * HH;       // DIN*BB       = 524288
    float* zp    = xT  + (size_t)DIN * BB;      // NSL*HH*BB    = 524288
    float* stats = zp  + (size_t)NSL * HH * BB; // 3*512        = 1536
    float* fA    = stats + 3 * 512;             // HH*BB        = 131072
    float* fB    = fA  + (size_t)HH * BB;       // 131072

    // 1) precompute reciprocal scales for all three layers
    prep_all_k<<<(HH*DIN + 2*HH*HH) / 256, 256, 0, stream>>>(s0, s1, s2, r0p, r1p, r2p);
    // 2) zero all stats slices (3 layers x 512)
    zero_k<<<6, 256, 0, stream>>>(stats);
    // 3) transpose x -> xT
    transpose_k<<<dim3(DIN/32, BB/32), dim3(32, 8), 0, stream>>>(x, xT);

    // ---- layer 0: DIN -> HH ----
    wav_partial_k<DIN><<<dim3(HH/4, NSL), 256, 0, stream>>>(xT, t0, r0p, w0, zp);
    silu_stats_k<<<HH, 256, 0, stream>>>(zp, stats);
    norm_k<<<HH, 256, 0, stream>>>(zp, stats, g0, b0, fA);

    // ---- layer 1: HH -> HH ----
    wav_partial_k<HH><<<dim3(HH/4, NSL), 256, 0, stream>>>(fA, t1, r1p, w1, zp);
    silu_stats_k<<<HH, 256, 0, stream>>>(zp, stats + 512);
    norm_k<<<HH, 256, 0, stream>>>(zp, stats + 512, g1, b1, fB);

    // ---- layer 2: HH -> HH ----
    wav_partial_k<HH><<<dim3(HH/4, NSL), 256, 0, stream>>>(fB, t2, r2p, w2, zp);
    silu_stats_k<<<HH, 256, 0, stream>>>(zp, stats + 1024);
    norm_k<<<HH, 256, 0, stream>>>(zp, stats + 1024, g2, b2, fA);

    // ---- classifier ----
    cls_k<<<1, 256, 0, stream>>>(fA, cw, cb, out);
}

// Round 2
// 258.399 us; speedup vs baseline: 1.2568x; 1.2568x over previous
//
#include <hip/hip_runtime.h>
#include <math.h>

// Problem geometry (fixed by setup_inputs)
#define BB   256   // batch
#define DIN  2048  // layer-0 input dim
#define HH   512   // hidden dim
#define NSL  8     // i-chunk split for wavelet kernels -> 1024 blocks = 4 waves/SIMD

#define NEG_HALF_LOG2E (-0.72134752044448170368f)
#define LOG2E           1.44269504088896340736f
#define LN2             0.69314718055994530942f

// ---------------------------------------------------------------------------
// prep: r = 1/(A_MIN + softplus(s) + 1e-8), tr = t*r   for all 3 layers
// ---------------------------------------------------------------------------
__global__ __launch_bounds__(256) void prep_all_k(
    const float* __restrict__ s0, const float* __restrict__ t0,
    const float* __restrict__ s1, const float* __restrict__ t1,
    const float* __restrict__ s2, const float* __restrict__ t2,
    float* __restrict__ r0, float* __restrict__ tr0,
    float* __restrict__ r1, float* __restrict__ tr1,
    float* __restrict__ r2, float* __restrict__ tr2)
{
    int i = blockIdx.x * 256 + threadIdx.x;
    const float *s, *t; float *r, *tr; int j;
    if (i < HH * DIN)            { s = s0; t = t0; r = r0; tr = tr0; j = i; }
    else if (i < HH*DIN + HH*HH) { s = s1; t = t1; r = r1; tr = tr1; j = i - HH*DIN; }
    else                         { s = s2; t = t2; r = r2; tr = tr2; j = i - (HH*DIN + HH*HH); }
    float v  = s[j];
    // softplus(v) = max(v,0) + ln(1 + exp(-|v|)), via exp2/log2 fast paths
    float e  = __builtin_amdgcn_exp2f(-fabsf(v) * LOG2E);
    float sp = fmaxf(v, 0.0f) + LN2 * __builtin_amdgcn_logf(1.0f + e);
    float rv = __builtin_amdgcn_rcpf(0.001f + sp + 1e-8f);
    r[j]  = rv;
    tr[j] = t[j] * rv;
}

// ---------------------------------------------------------------------------
// transpose x [BB][DIN] -> xT [DIN][BB]
// ---------------------------------------------------------------------------
__global__ __launch_bounds__(256) void transpose_k(
    const float* __restrict__ in, float* __restrict__ out)
{
    __shared__ float tile[32][33];
    int c0 = blockIdx.x * 32;
    int r0 = blockIdx.y * 32;
    int tx = threadIdx.x, ty = threadIdx.y;   // block (32, 8)
#pragma unroll
    for (int k = 0; k < 4; k++)
        tile[ty + 8*k][tx] = in[(size_t)(r0 + ty + 8*k) * DIN + c0 + tx];
    __syncthreads();
#pragma unroll
    for (int k = 0; k < 4; k++)
        out[(size_t)(c0 + ty + 8*k) * BB + r0 + tx] = tile[tx][ty + 8*k];
}

// ---------------------------------------------------------------------------
// wavelet partial sums, software-pipelined.
// fin: [D][BB]; rr/trr/ww: [HH][D]; zp: [NSL][HH][BB]
// block: 256 threads = b; 4 o-rows per thread. grid: (HH/4, NSL)
// ---------------------------------------------------------------------------
#define EV(X, Rv, Tv, Wv, acc) {                                   \
    float d_  = fmaf((X), (Rv), -(Tv));                            \
    float s2_ = d_ * d_;                                           \
    float e_  = __builtin_amdgcn_exp2f(s2_ * NEG_HALF_LOG2E);      \
    float p_  = fmaf(-(Wv), s2_, (Wv));                            \
    acc = fmaf(p_, e_, acc); }

#define EV4(X0,X1,X2,X3, R,T,W, acc)    \
    EV(X0, R.x, T.x, W.x, acc)          \
    EV(X1, R.y, T.y, W.y, acc)          \
    EV(X2, R.z, T.z, W.z, acc)          \
    EV(X3, R.w, T.w, W.w, acc)

template<int D>
__global__ __launch_bounds__(256, 4) void wav_k(
    const float* __restrict__ fin,
    const float* __restrict__ rr,
    const float* __restrict__ trr,
    const float* __restrict__ ww,
    float* __restrict__ zp)
{
    constexpr int CH = D / NSL;
    const int o0 = blockIdx.x * 4;
    const int i0 = blockIdx.y * CH;
    const int b  = threadIdx.x;

    const float* __restrict__ xc  = fin + b;
    const float* __restrict__ rp0 = rr  + (size_t)(o0 + 0) * D;
    const float* __restrict__ rp1 = rr  + (size_t)(o0 + 1) * D;
    const float* __restrict__ rp2 = rr  + (size_t)(o0 + 2) * D;
    const float* __restrict__ rp3 = rr  + (size_t)(o0 + 3) * D;
    const float* __restrict__ tp0 = trr + (size_t)(o0 + 0) * D;
    const float* __restrict__ tp1 = trr + (size_t)(o0 + 1) * D;
    const float* __restrict__ tp2 = trr + (size_t)(o0 + 2) * D;
    const float* __restrict__ tp3 = trr + (size_t)(o0 + 3) * D;
    const float* __restrict__ wp0 = ww  + (size_t)(o0 + 0) * D;
    const float* __restrict__ wp1 = ww  + (size_t)(o0 + 1) * D;
    const float* __restrict__ wp2 = ww  + (size_t)(o0 + 2) * D;
    const float* __restrict__ wp3 = ww  + (size_t)(o0 + 3) * D;

    float a0 = 0.f, a1 = 0.f, a2 = 0.f, a3 = 0.f;

    // current-group registers
    float  x0, x1, x2, x3;
    float4 R0, R1, R2, R3, T0, T1, T2, T3, W0, W1, W2, W3;

#define LD_X(i, X0_,X1_,X2_,X3_)                   \
    X0_ = xc[(size_t)((i) + 0) * BB];              \
    X1_ = xc[(size_t)((i) + 1) * BB];              \
    X2_ = xc[(size_t)((i) + 2) * BB];              \
    X3_ = xc[(size_t)((i) + 3) * BB];

#define LD_P(i, R_,T_,W_, rp_,tp_,wp_)             \
    R_ = *(const float4*)((rp_) + (i));            \
    T_ = *(const float4*)((tp_) + (i));            \
    W_ = *(const float4*)((wp_) + (i));

    LD_X(i0, x0, x1, x2, x3)
    LD_P(i0, R0, T0, W0, rp0, tp0, wp0)
    LD_P(i0, R1, T1, W1, rp1, tp1, wp1)
    LD_P(i0, R2, T2, W2, rp2, tp2, wp2)
    LD_P(i0, R3, T3, W3, rp3, tp3, wp3)

    for (int i = i0; i < i0 + CH - 4; i += 4) {
        // prefetch next group
        float  nx0, nx1, nx2, nx3;
        float4 nR0, nR1, nR2, nR3, nT0, nT1, nT2, nT3, nW0, nW1, nW2, nW3;
        LD_X(i + 4, nx0, nx1, nx2, nx3)
        LD_P(i + 4, nR0, nT0, nW0, rp0, tp0, wp0)
        LD_P(i + 4, nR1, nT1, nW1, rp1, tp1, wp1)
        LD_P(i + 4, nR2, nT2, nW2, rp2, tp2, wp2)
        LD_P(i + 4, nR3, nT3, nW3, rp3, tp3, wp3)

        // compute current group
        EV4(x0, x1, x2, x3, R0, T0, W0, a0)
        EV4(x0, x1, x2, x3, R1, T1, W1, a1)
        EV4(x0, x1, x2, x3, R2, T2, W2, a2)
        EV4(x0, x1, x2, x3, R3, T3, W3, a3)

        // rotate
        x0 = nx0; x1 = nx1; x2 = nx2; x3 = nx3;
        R0 = nR0; R1 = nR1; R2 = nR2; R3 = nR3;
        T0 = nT0; T1 = nT1; T2 = nT2; T3 = nT3;
        W0 = nW0; W1 = nW1; W2 = nW2; W3 = nW3;
    }

    // final group
    EV4(x0, x1, x2, x3, R0, T0, W0, a0)
    EV4(x0, x1, x2, x3, R1, T1, W1, a1)
    EV4(x0, x1, x2, x3, R2, T2, W2, a2)
    EV4(x0, x1, x2, x3, R3, T3, W3, a3)

    float* __restrict__ zs = zp + (size_t)blockIdx.y * (HH * BB);
    zs[(size_t)(o0 + 0) * BB + b] = a0;
    zs[(size_t)(o0 + 1) * BB + b] = a1;
    zs[(size_t)(o0 + 2) * BB + b] = a2;
    zs[(size_t)(o0 + 3) * BB + b] = a3;
}

// ---------------------------------------------------------------------------
// finish: combine NSL partials + SiLU + layernorm (block per batch b)
// zp: [NSL][HH][BB] -> fout[o][b] = g[o]*(v-m)*rsqrt(var+eps)+be[o]
// grid BB, block 256 (each thread handles o = t and t+256)
// ---------------------------------------------------------------------------
__global__ __launch_bounds__(256) void finish_k(
    const float* __restrict__ zp, const float* __restrict__ g,
    const float* __restrict__ be, float* __restrict__ fout)
{
    const int b = blockIdx.x, t = threadIdx.x;
    float y0 = 0.f, y1 = 0.f;
#pragma unroll
    for (int sl = 0; sl < NSL; sl++) {
        y0 += zp[(size_t)sl * (HH*BB) + (size_t)t         * BB + b];
        y1 += zp[(size_t)sl * (HH*BB) + (size_t)(t + 256) * BB + b];
    }
    float v0 = y0 * __builtin_amdgcn_rcpf(1.f + __builtin_amdgcn_exp2f(-y0 * LOG2E));
    float v1 = y1 * __builtin_amdgcn_rcpf(1.f + __builtin_amdgcn_exp2f(-y1 * LOG2E));

    float sum = v0 + v1, ss = v0*v0 + v1*v1;
#pragma unroll
    for (int off = 32; off; off >>= 1) {
        sum += __shfl_xor(sum, off);
        ss  += __shfl_xor(ss,  off);
    }
    __shared__ float ls[8];
    int wid = t >> 6;
    if ((t & 63) == 0) { ls[wid] = sum; ls[4 + wid] = ss; }
    __syncthreads();
    sum = ls[0] + ls[1] + ls[2] + ls[3];
    ss  = ls[4] + ls[5] + ls[6] + ls[7];

    float m   = sum * (1.0f / HH);
    float var = ss  * (1.0f / HH) - m * m;
    float rs  = rsqrtf(var + 1e-5f);
    fout[(size_t)t         * BB + b] = g[t]       * (v0 - m) * rs + be[t];
    fout[(size_t)(t + 256) * BB + b] = g[t + 256] * (v1 - m) * rs + be[t + 256];
}

// ---------------------------------------------------------------------------
// classifier: out[b][c] = sum_o f[o][b]*cw[c][o] + cb[c]   (C=2)
// ---------------------------------------------------------------------------
__global__ __launch_bounds__(256) void cls_k(
    const float* __restrict__ f, const float* __restrict__ cw,
    const float* __restrict__ cb, float* __restrict__ out)
{
    int b = threadIdx.x;
    float a0 = cb[0], a1 = cb[1];
#pragma unroll 8
    for (int o = 0; o < HH; o++) {
        float v = f[(size_t)o * BB + b];
        a0 = fmaf(v, cw[o],      a0);
        a1 = fmaf(v, cw[HH + o], a1);
    }
    out[b * 2 + 0] = a0;
    out[b * 2 + 1] = a1;
}

// ---------------------------------------------------------------------------
extern "C" void kernel_launch(void* const* d_in, const int* in_sizes, int n_in,
                              void* d_out, int out_size, void* d_ws, size_t ws_size,
                              hipStream_t stream)
{
    const float* x  = (const float*)d_in[0];
    const float* t0 = (const float*)d_in[1];
    const float* s0 = (const float*)d_in[2];
    const float* w0 = (const float*)d_in[3];
    const float* g0 = (const float*)d_in[4];
    const float* b0 = (const float*)d_in[5];
    const float* t1 = (const float*)d_in[6];
    const float* s1 = (const float*)d_in[7];
    const float* w1 = (const float*)d_in[8];
    const float* g1 = (const float*)d_in[9];
    const float* b1 = (const float*)d_in[10];
    const float* t2 = (const float*)d_in[11];
    const float* s2 = (const float*)d_in[12];
    const float* w2 = (const float*)d_in[13];
    const float* g2 = (const float*)d_in[14];
    const float* b2 = (const float*)d_in[15];
    const float* cw = (const float*)d_in[16];
    const float* cb = (const float*)d_in[17];
    float* out = (float*)d_out;

    float* ws = (float*)d_ws;
    // workspace layout (floats), ~19.9 MB total
    float* r0p  = ws;                            // 1048576
    float* tr0p = r0p  + (size_t)HH * DIN;       // 1048576
    float* r1p  = tr0p + (size_t)HH * DIN;       // 262144
    float* tr1p = r1p  + (size_t)HH * HH;        // 262144
    float* r2p  = tr1p + (size_t)HH * HH;        // 262144
    float* tr2p = r2p  + (size_t)HH * HH;        // 262144
    float* xT   = tr2p + (size_t)HH * HH;        // 524288
    float* zp   = xT   + (size_t)DIN * BB;       // NSL*HH*BB = 1048576
    float* fA   = zp   + (size_t)NSL * HH * BB;  // 131072
    float* fB   = fA   + (size_t)HH * BB;        // 131072

    prep_all_k<<<(HH*DIN + 2*HH*HH) / 256, 256, 0, stream>>>(
        s0, t0, s1, t1, s2, t2, r0p, tr0p, r1p, tr1p, r2p, tr2p);
    transpose_k<<<dim3(DIN/32, BB/32), dim3(32, 8), 0, stream>>>(x, xT);

    // ---- layer 0: DIN -> HH ----
    wav_k<DIN><<<dim3(HH/4, NSL), 256, 0, stream>>>(xT, r0p, tr0p, w0, zp);
    finish_k<<<BB, 256, 0, stream>>>(zp, g0, b0, fA);

    // ---- layer 1: HH -> HH ----
    wav_k<HH><<<dim3(HH/4, NSL), 256, 0, stream>>>(fA, r1p, tr1p, w1, zp);
    finish_k<<<BB, 256, 0, stream>>>(zp, g1, b1, fB);

    // ---- layer 2: HH -> HH ----
    wav_k<HH><<<dim3(HH/4, NSL), 256, 0, stream>>>(fB, r2p, tr2p, w2, zp);
    finish_k<<<BB, 256, 0, stream>>>(zp, g2, b2, fA);

    // ---- classifier ----
    cls_k<<<1, 256, 0, stream>>>(fA, cw, cb, out);
}

// Round 4
// 210.705 us; speedup vs baseline: 1.5413x; 1.2264x over previous
//
#include <hip/hip_runtime.h>
#include <math.h>

// Problem geometry (fixed by setup_inputs)
#define BB   256   // batch
#define DIN  2048  // layer-0 input dim
#define HH   512   // hidden dim
#define NSL  16    // i-slice split -> 2048 blocks = 8 blocks/CU = 8 waves/SIMD

#define NEG_HALF_LOG2E (-0.72134752044448170368f)
#define LOG2E           1.44269504088896340736f
#define LN2             0.69314718055994530942f

// ---------------------------------------------------------------------------
// pack one param element into P[q][g][oo][12] = { r[4], t*r[4], w[4] }
// r = 1/(A_MIN + softplus(s) + 1e-8)
// ---------------------------------------------------------------------------
__device__ __forceinline__ void pack_one(
    const float* __restrict__ s, const float* __restrict__ t,
    const float* __restrict__ w, float* __restrict__ P, int lg, int jj)
{
    int D  = 1 << lg;
    int o  = jj >> lg, i = jj & (D - 1);
    int q  = o >> 2,  oo = o & 3;
    int g  = i >> 2,  rr = i & 3;

    float v  = s[jj];
    float e  = __builtin_amdgcn_exp2f(-fabsf(v) * LOG2E);
    float sp = fmaxf(v, 0.0f) + LN2 * __builtin_amdgcn_logf(1.0f + e);
    float rv = __builtin_amdgcn_rcpf(0.001f + sp + 1e-8f);

    size_t base = ((size_t)q * (D >> 2) + g) * 48 + oo * 12;
    P[base + rr]     = rv;
    P[base + 4 + rr] = t[jj] * rv;
    P[base + 8 + rr] = w[jj];
}

// layer 0 pack + zero the atomic accumulator (acc has HH*BB floats)
__global__ __launch_bounds__(256) void pack0_k(
    const float* __restrict__ s0, const float* __restrict__ t0,
    const float* __restrict__ w0, float* __restrict__ P0,
    float* __restrict__ acc)
{
    int j = blockIdx.x * 256 + threadIdx.x;   // grid covers HH*DIN
    pack_one(s0, t0, w0, P0, 11, j);
    if (j < HH * BB) acc[j] = 0.0f;
}

// layers 1+2 pack — MUST run after wav0 (P1/P2 alias the P0 region)
__global__ __launch_bounds__(256) void pack12_k(
    const float* __restrict__ s1, const float* __restrict__ t1, const float* __restrict__ w1,
    const float* __restrict__ s2, const float* __restrict__ t2, const float* __restrict__ w2,
    float* __restrict__ P1, float* __restrict__ P2)
{
    int j = blockIdx.x * 256 + threadIdx.x;   // grid covers 2*HH*HH
    if (j < HH * HH) pack_one(s1, t1, w1, P1, 9, j);
    else             pack_one(s2, t2, w2, P2, 9, j - HH * HH);
}

// ---------------------------------------------------------------------------
// transpose x [BB][DIN] -> x4 [DIN/4][BB] (float4 = 4 consecutive i for one b)
// ---------------------------------------------------------------------------
__global__ __launch_bounds__(256) void transpose_k(
    const float* __restrict__ in, float4* __restrict__ out4)
{
    __shared__ float tile[32][33];
    int c0 = blockIdx.x * 32;           // DIN tile
    int r0 = blockIdx.y * 32;           // BB tile
    int tx = threadIdx.x, ty = threadIdx.y;   // block (32, 8)
#pragma unroll
    for (int k = 0; k < 4; k++)
        tile[ty + 8*k][tx] = in[(size_t)(r0 + ty + 8*k) * DIN + c0 + tx];  // tile[b][c]
    __syncthreads();
    float4 v = make_float4(tile[tx][4*ty + 0], tile[tx][4*ty + 1],
                           tile[tx][4*ty + 2], tile[tx][4*ty + 3]);
    out4[(size_t)(c0/4 + ty) * BB + (r0 + tx)] = v;
}

// ---------------------------------------------------------------------------
// wavelet partial sums -> atomic accumulate into acc[o][b]
// x4: [D/4][BB] float4; P: [HH/4][D/4][48]; acc: [HH][BB]
// block: 256 threads = b; 4 o-rows per thread. grid: (HH/4, NSL)
// ---------------------------------------------------------------------------
#define EV(X, Rv, Tv, Wv, a) {                                     \
    float d_  = fmaf((X), (Rv), -(Tv));                            \
    float s2_ = d_ * d_;                                           \
    float e_  = __builtin_amdgcn_exp2f(s2_ * NEG_HALF_LOG2E);      \
    float p_  = fmaf(-(Wv), s2_, (Wv));                            \
    a = fmaf(p_, e_, a); }

#define EV4(XV, R,T,W, a)        \
    EV(XV.x, R.x, T.x, W.x, a)   \
    EV(XV.y, R.y, T.y, W.y, a)   \
    EV(XV.z, R.z, T.z, W.z, a)   \
    EV(XV.w, R.w, T.w, W.w, a)

template<int D>
__global__ __launch_bounds__(256, 8) void wav_k(
    const float4* __restrict__ x4,
    const float*  __restrict__ P,
    float* __restrict__ acc)
{
    constexpr int G = (D / 4) / NSL;      // groups per block (32 or 8)
    const int q  = blockIdx.x;            // o-quad
    const int sl = blockIdx.y;            // i-slice
    const int b  = threadIdx.x;

    const float*  pp = P  + ((size_t)q * (D/4) + (size_t)sl * G) * 48;
    const float4* xp = x4 + (size_t)sl * G * BB + b;

    float a0 = 0.f, a1 = 0.f, a2 = 0.f, a3 = 0.f;

#pragma unroll 2
    for (int g = 0; g < G; ++g) {
        const float* pb = pp + (size_t)g * 48;
        float4 xv = xp[(size_t)g * BB];
        float4 R0 = *(const float4*)(pb +  0);
        float4 T0 = *(const float4*)(pb +  4);
        float4 W0 = *(const float4*)(pb +  8);
        float4 R1 = *(const float4*)(pb + 12);
        float4 T1 = *(const float4*)(pb + 16);
        float4 W1 = *(const float4*)(pb + 20);
        float4 R2 = *(const float4*)(pb + 24);
        float4 T2 = *(const float4*)(pb + 28);
        float4 W2 = *(const float4*)(pb + 32);
        float4 R3 = *(const float4*)(pb + 36);
        float4 T3 = *(const float4*)(pb + 40);
        float4 W3 = *(const float4*)(pb + 44);

        EV4(xv, R0, T0, W0, a0)
        EV4(xv, R1, T1, W1, a1)
        EV4(xv, R2, T2, W2, a2)
        EV4(xv, R3, T3, W3, a3)
    }

    float* dst = acc + (size_t)(4 * q) * BB + b;
    unsafeAtomicAdd(dst,          a0);
    unsafeAtomicAdd(dst + BB,     a1);
    unsafeAtomicAdd(dst + 2*BB,   a2);
    unsafeAtomicAdd(dst + 3*BB,   a3);
}

// ---------------------------------------------------------------------------
// finish: SiLU + layernorm over acc column b; re-zero acc for next layer.
// acc: [HH][BB]; fout4: [HH/4][BB] float4 (4 consecutive o for one b)
// grid BB, block 128 (thread t = o-quad)
// ---------------------------------------------------------------------------
__device__ __forceinline__ float silu_f(float y)
{
    return y * __builtin_amdgcn_rcpf(1.f + __builtin_amdgcn_exp2f(-y * LOG2E));
}

__global__ __launch_bounds__(128) void finish_k(
    float* __restrict__ acc, const float* __restrict__ g,
    const float* __restrict__ be, float4* __restrict__ fout4)
{
    const int b = blockIdx.x, t = threadIdx.x;
    float* ap = acc + (size_t)(4 * t) * BB + b;
    float y0 = ap[0], y1 = ap[BB], y2 = ap[2*BB], y3 = ap[3*BB];
    ap[0] = 0.f; ap[BB] = 0.f; ap[2*BB] = 0.f; ap[3*BB] = 0.f;   // re-zero own column

    float v0 = silu_f(y0), v1 = silu_f(y1), v2 = silu_f(y2), v3 = silu_f(y3);

    float sum = v0 + v1 + v2 + v3;
    float ss  = v0*v0 + v1*v1 + v2*v2 + v3*v3;
#pragma unroll
    for (int off = 32; off; off >>= 1) {
        sum += __shfl_xor(sum, off);
        ss  += __shfl_xor(ss,  off);
    }
    __shared__ float ls[4];
    int wid = t >> 6;
    if ((t & 63) == 0) { ls[wid] = sum; ls[2 + wid] = ss; }
    __syncthreads();
    sum = ls[0] + ls[1];
    ss  = ls[2] + ls[3];

    float m   = sum * (1.0f / HH);
    float var = ss  * (1.0f / HH) - m * m;
    float rs  = rsqrtf(var + 1e-5f);

    float4 gv = ((const float4*)g)[t];
    float4 bv = ((const float4*)be)[t];
    fout4[(size_t)t * BB + b] = make_float4(gv.x * (v0 - m) * rs + bv.x,
                                            gv.y * (v1 - m) * rs + bv.y,
                                            gv.z * (v2 - m) * rs + bv.z,
                                            gv.w * (v3 - m) * rs + bv.w);
}

// ---------------------------------------------------------------------------
// finish + classifier (layer 2): out[b][c] = sum_o f[o]*cw[c][o] + cb[c]
// ---------------------------------------------------------------------------
__global__ __launch_bounds__(128) void finish_cls_k(
    const float* __restrict__ acc, const float* __restrict__ g,
    const float* __restrict__ be, const float* __restrict__ cw,
    const float* __restrict__ cb, float* __restrict__ out)
{
    const int b = blockIdx.x, t = threadIdx.x;
    const float* ap = acc + (size_t)(4 * t) * BB + b;
    float v0 = silu_f(ap[0]), v1 = silu_f(ap[BB]), v2 = silu_f(ap[2*BB]), v3 = silu_f(ap[3*BB]);

    float sum = v0 + v1 + v2 + v3;
    float ss  = v0*v0 + v1*v1 + v2*v2 + v3*v3;
#pragma unroll
    for (int off = 32; off; off >>= 1) {
        sum += __shfl_xor(sum, off);
        ss  += __shfl_xor(ss,  off);
    }
    __shared__ float ls[4];
    int wid = t >> 6;
    if ((t & 63) == 0) { ls[wid] = sum; ls[2 + wid] = ss; }
    __syncthreads();
    sum = ls[0] + ls[1];
    ss  = ls[2] + ls[3];

    float m   = sum * (1.0f / HH);
    float var = ss  * (1.0f / HH) - m * m;
    float rs  = rsqrtf(var + 1e-5f);

    float4 gv = ((const float4*)g)[t];
    float4 bv = ((const float4*)be)[t];
    float f0 = gv.x * (v0 - m) * rs + bv.x;
    float f1 = gv.y * (v1 - m) * rs + bv.y;
    float f2 = gv.z * (v2 - m) * rs + bv.z;
    float f3 = gv.w * (v3 - m) * rs + bv.w;

    float4 ca  = ((const float4*)cw)[t];          // classifier row 0
    float4 cbv = ((const float4*)cw)[HH/4 + t];   // classifier row 1
    float c0 = f0*ca.x  + f1*ca.y  + f2*ca.z  + f3*ca.w;
    float c1 = f0*cbv.x + f1*cbv.y + f2*cbv.z + f3*cbv.w;
#pragma unroll
    for (int off = 32; off; off >>= 1) {
        c0 += __shfl_xor(c0, off);
        c1 += __shfl_xor(c1, off);
    }
    __syncthreads();
    if ((t & 63) == 0) { ls[wid] = c0; ls[2 + wid] = c1; }
    __syncthreads();
    if (t == 0) {
        out[b * 2 + 0] = ls[0] + ls[1] + cb[0];
        out[b * 2 + 1] = ls[2] + ls[3] + cb[1];
    }
}

// ---------------------------------------------------------------------------
extern "C" void kernel_launch(void* const* d_in, const int* in_sizes, int n_in,
                              void* d_out, int out_size, void* d_ws, size_t ws_size,
                              hipStream_t stream)
{
    const float* x  = (const float*)d_in[0];
    const float* t0 = (const float*)d_in[1];
    const float* s0 = (const float*)d_in[2];
    const float* w0 = (const float*)d_in[3];
    const float* g0 = (const float*)d_in[4];
    const float* b0 = (const float*)d_in[5];
    const float* t1 = (const float*)d_in[6];
    const float* s1 = (const float*)d_in[7];
    const float* w1 = (const float*)d_in[8];
    const float* g1 = (const float*)d_in[9];
    const float* b1 = (const float*)d_in[10];
    const float* t2 = (const float*)d_in[11];
    const float* s2 = (const float*)d_in[12];
    const float* w2 = (const float*)d_in[13];
    const float* g2 = (const float*)d_in[14];
    const float* b2 = (const float*)d_in[15];
    const float* cw = (const float*)d_in[16];
    const float* cb = (const float*)d_in[17];
    float* out = (float*)d_out;

    float* ws = (float*)d_ws;
    // workspace layout (floats), total 3,932,160 fl = 15.73 MB (proven-safe < 19.9 MB)
    float*  P0  = ws;                                   // 3,145,728 (12.6 MB)
    float*  P1  = ws;                                   // aliases P0 (packed AFTER wav0)
    float*  P2  = ws + (size_t)HH * HH * 3;             // 786,432..1,572,864 (inside P0)
    float4* x4  = (float4*)(ws + (size_t)HH * DIN * 3); // 524,288 fl (131072 f4)
    float*  acc = ws + (size_t)HH * DIN * 3 + (size_t)(DIN/4) * BB * 4;  // 131,072 fl
    float4* fA  = (float4*)(acc + (size_t)HH * BB);     // 131,072 fl
    float4* fB  = x4;                                   // reuse x4 (dead after wav0)

    // pack layer 0 + zero acc; transpose x
    pack0_k<<<HH*DIN / 256, 256, 0, stream>>>(s0, t0, w0, P0, acc);
    transpose_k<<<dim3(DIN/32, BB/32), dim3(32, 8), 0, stream>>>(x, x4);

    // ---- layer 0: DIN -> HH ----
    wav_k<DIN><<<dim3(HH/4, NSL), 256, 0, stream>>>(x4, P0, acc);
    // pack layers 1+2 into the (now dead) P0 region
    pack12_k<<<2*HH*HH / 256, 256, 0, stream>>>(s1, t1, w1, s2, t2, w2, P1, P2);
    finish_k<<<BB, 128, 0, stream>>>(acc, g0, b0, fA);

    // ---- layer 1: HH -> HH ----
    wav_k<HH><<<dim3(HH/4, NSL), 256, 0, stream>>>(fA, P1, acc);
    finish_k<<<BB, 128, 0, stream>>>(acc, g1, b1, fB);

    // ---- layer 2: HH -> HH + classifier ----
    wav_k<HH><<<dim3(HH/4, NSL), 256, 0, stream>>>(fB, P2, acc);
    finish_cls_k<<<BB, 128, 0, stream>>>(acc, g2, b2, cw, cb, out);
}